// Round 9
// baseline (3303.120 us; speedup 1.0000x reference)
//
#include <hip/hip_runtime.h>
#include <cmath>

// B=32, T=128, E=512, H=1024, 4H=4096
typedef __attribute__((ext_vector_type(8))) short short8;
typedef __attribute__((ext_vector_type(4))) float f32x4;
typedef unsigned long long u64;

__device__ inline short bf16r(float x) {
  union { float f; unsigned u; } v; v.f = x;
  unsigned r = (v.u + 0x7fff + ((v.u >> 16) & 1)) >> 16;
  return (short)r;
}
__device__ inline float bf2f(short s) {
  union { unsigned u; float f; } v; v.u = ((unsigned)(unsigned short)s) << 16;
  return v.f;
}

// hx layout: [t][chunk c=u>>4][b(32)][u&15] bf16 ; 129 buffers of 32768 shorts.
// ---------- small prep kernels ----------
__global__ __launch_bounds__(256) void init2(const float* __restrict__ h0,
                                             const float* __restrict__ c0,
                                             short* __restrict__ hx0,
                                             float* __restrict__ c) {
  int idx = blockIdx.x * 256 + threadIdx.x;  // (b,u) row-major
  int b = idx >> 10, u = idx & 1023;
  hx0[(u >> 4) * 512 + b * 16 + (u & 15)] = bf16r(h0[idx]);
  c[idx] = c0[idx];
}

__global__ __launch_bounds__(256) void finalize2(const short* __restrict__ hx128,
                                                 const float* __restrict__ c,
                                                 float* __restrict__ out) {
  int idx = blockIdx.x * 256 + threadIdx.x;  // (b,u)
  int b = idx >> 10, u = idx & 1023;
  out[idx] = bf2f(hx128[(u >> 4) * 512 + b * 16 + (u & 15)]);
  out[32768 + idx] = c[idx];
}

__global__ __launch_bounds__(256) void zero_cnt(unsigned* __restrict__ c) {
  c[blockIdx.x * 256 + threadIdx.x] = 0u;  // 16 blocks -> 4096 u32
}

// x (B,T,E) fp32 -> xb rows r=t*32+b, (4096,512) bf16
__global__ __launch_bounds__(256) void cast_x(const float* __restrict__ x,
                                              short* __restrict__ xb) {
  int idx = blockIdx.x * 256 + threadIdx.x;
  int e = idx & 511, t = (idx >> 9) & 127, b = idx >> 16;
  xb[(((t << 5) + b) << 9) + e] = bf16r(x[idx]);
}

// permuted biases: bp[l][n'] = b_l[(n'&3)*1024 + (n'>>2)]
__global__ __launch_bounds__(256) void bias_perm(const float* __restrict__ b1,
                                                 const float* __restrict__ b2,
                                                 const float* __restrict__ b3,
                                                 const float* __restrict__ b4,
                                                 float* __restrict__ bp) {
  int idx = blockIdx.x * 256 + threadIdx.x;  // 0..16383
  int l = idx >> 12, c = idx & 4095;
  const float* s = (l == 0) ? b1 : (l == 1) ? b2 : (l == 2) ? b3 : b4;
  bp[idx] = s[((c & 3) << 10) | (c >> 2)];
}

// in fp32 (R,C) -> out bf16 (C,R); GPERM: out-row n' = (c&1023)*4 + (c>>10)
template <bool GPERM>
__global__ __launch_bounds__(256) void transpose_cast(const float* __restrict__ in,
                                                      short* __restrict__ out,
                                                      int R, int C) {
  __shared__ float tile[32][33];
  int c0 = blockIdx.x * 32, r0 = blockIdx.y * 32;
  int x = threadIdx.x & 31, y = threadIdx.x >> 5;
#pragma unroll
  for (int i = 0; i < 4; ++i)
    tile[y + i * 8][x] = in[(size_t)(r0 + y + i * 8) * C + c0 + x];
  __syncthreads();
#pragma unroll
  for (int i = 0; i < 4; ++i) {
    int c = c0 + y + i * 8;
    int n = GPERM ? (((c & 1023) << 2) | (c >> 10)) : c;
    out[(size_t)n * R + r0 + x] = bf16r(tile[x][y + i * 8]);
  }
}

// ---------- bf16 MFMA GEMM ----------
// A: if AHX, A points at hx-layout sequence (row r=t*32+b, k=unit); else (M,K) rm.
// Bt (N,K) bf16 rm; C = A·Bt^T + bias
// MODE 1: fp32 out, row-major [r][col] ; MODE 2: bf16 rm + relu ; MODE 3: fp32 (B,T,E)
template <int MODE, bool AHX>
__global__ __launch_bounds__(256) void gemm_bf16(const short* __restrict__ A,
                                                 const short* __restrict__ Bt,
                                                 const float* __restrict__ bias,
                                                 void* __restrict__ Cout,
                                                 int M, int N, int K) {
  __shared__ short As[128 * 40];
  __shared__ short Bs[128 * 40];
  const int tid = threadIdx.x;
  const int lane = tid & 63, wave = tid >> 6;
  const int lrow = lane & 15, lk = lane >> 4;
  const int m0 = (wave >> 1) * 64, n0 = (wave & 1) * 64;
  const int r = tid & 127, half = tid >> 7;
  const int mbase = blockIdx.y * 128, nbase = blockIdx.x * 128;

  f32x4 acc[4][4] = {};

  const short* Ab = A + (size_t)(mbase + r) * K + half * 16;
  const short* Ahx =
      A + (size_t)((mbase + r) >> 5) * 32768 + half * 512 + ((mbase + r) & 31) * 16;
  const short* Bb = Bt + (size_t)(nbase + r) * K + half * 16;
  short* AsW = As + r * 40 + half * 16;
  short* BsW = Bs + r * 40 + half * 16;

  for (int k0 = 0; k0 < K; k0 += 32) {
    short8 av0, av1;
    if constexpr (AHX) {
      const short* ap = Ahx + (k0 >> 4) * 512;
      av0 = *(const short8*)ap;
      av1 = *(const short8*)(ap + 8);
    } else {
      av0 = *(const short8*)(Ab + k0);
      av1 = *(const short8*)(Ab + k0 + 8);
    }
    short8 bv0 = *(const short8*)(Bb + k0);
    short8 bv1 = *(const short8*)(Bb + k0 + 8);
    __syncthreads();
    *(short8*)(AsW) = av0;
    *(short8*)(AsW + 8) = av1;
    *(short8*)(BsW) = bv0;
    *(short8*)(BsW + 8) = bv1;
    __syncthreads();
    short8 af[4], bfr[4];
#pragma unroll
    for (int i = 0; i < 4; ++i)
      af[i] = *(const short8*)(As + (m0 + i * 16 + lrow) * 40 + lk * 8);
#pragma unroll
    for (int i = 0; i < 4; ++i)
      bfr[i] = *(const short8*)(Bs + (n0 + i * 16 + lrow) * 40 + lk * 8);
#pragma unroll
    for (int i = 0; i < 4; ++i)
#pragma unroll
      for (int j = 0; j < 4; ++j)
        acc[i][j] = __builtin_amdgcn_mfma_f32_16x16x32_bf16(af[i], bfr[j],
                                                            acc[i][j], 0, 0, 0);
  }

#pragma unroll
  for (int i = 0; i < 4; ++i) {
    const int grow0 = mbase + m0 + i * 16 + lk * 4;
#pragma unroll
    for (int j = 0; j < 4; ++j) {
      const int gcol = nbase + n0 + j * 16 + lrow;
      const float bv = bias[gcol];
      f32x4 v = acc[i][j];
      if constexpr (MODE == 1) {
        float* o = (float*)Cout;
#pragma unroll
        for (int jj = 0; jj < 4; ++jj)
          o[(size_t)(grow0 + jj) * N + gcol] = v[jj] + bv;
      } else if constexpr (MODE == 2) {
        short* o = (short*)Cout;
#pragma unroll
        for (int jj = 0; jj < 4; ++jj)
          o[(size_t)(grow0 + jj) * N + gcol] = bf16r(fmaxf(v[jj] + bv, 0.f));
      } else {
        float* o = (float*)Cout;
#pragma unroll
        for (int jj = 0; jj < 4; ++jj) {
          int rr = grow0 + jj;
          int orow = ((rr & 31) << 7) | (rr >> 5);
          o[(size_t)orow * N + gcol] = v[jj] + bv;
        }
      }
    }
  }
}

// ---------- persistent recurrent kernel (whole layer, 128 steps) ----------
// xWp [t*32+b][col] fp32 row-major (READ for this layer; if FUSE, REWRITTEN
// in place with next layer's xW = h_l[t]·W_{l+1} + b_{l+1} — per-element
// read(step s-1 prefetch) strictly precedes write(step s+1), same thread).
// Utp (4096,1024) bf16 gate-interleaved; Wf: same for W of next layer;
// hx (129,32768) bf16 exchange; cst (32,1024) fp32.
// 64 blocks x 256 threads; swapped MFMA (gates in-lane); xw-MFMA placed in the
// post-flag detect window, reading Hs (= h[t-1]) before it is restaged.
#define PBLK 64
template <bool FUSE>
__global__ __launch_bounds__(256) void lstm_persist(
    float* __restrict__ xWp, const short* __restrict__ Utp,
    const short* __restrict__ Wf, const float* __restrict__ bxw,
    short* __restrict__ hx, float* __restrict__ cst,
    unsigned* __restrict__ arr, int ebase) {
  __shared__ short Hs[32768];  // 64KB: h_{t-1} in chunk layout
  const int tid = threadIdx.x;
  const int lane = tid & 63, wave = tid >> 6;
  const int lrow = lane & 15, lk = lane >> 4;
  const int bid = blockIdx.x;
  const int ucol = bid * 64 + wave * 16 + lrow;    // A-operand row (U/W col)
  const int col4 = bid * 64 + wave * 16 + lk * 4;  // first z-col of this lane
  const int u = bid * 16 + wave * 4 + lk;          // unit owned by this lane

  // U fragment -> registers
  short8 ureg[32];
  {
    const short* Ub = Utp + (size_t)ucol * 1024 + lk * 8;
#pragma unroll
    for (int j = 0; j < 32; ++j) ureg[j] = *(const short8*)(Ub + j * 32);
  }

  float creg0 = cst[lrow * 1024 + u];
  float creg1 = cst[(lrow + 16) * 1024 + u];

  f32x4 bw = {};
  if constexpr (FUSE) bw = *(const f32x4*)(bxw + col4);
  const short* Wb = Wf + (size_t)ucol * 1024 + lk * 8;

  f32x4 cur0 = *(const f32x4*)(xWp + (size_t)lrow * 4096 + col4);
  f32x4 cur1 = *(const f32x4*)(xWp + (size_t)(lrow + 16) * 4096 + col4);

  for (int t = 0; t < 128; ++t) {
    const unsigned ep = (unsigned)(ebase + t);
    const char* src = (const char*)(hx + (size_t)t * 32768) + tid * 16;
    char* dst = (char*)Hs + tid * 16;

    if (t) {
      if (tid < 32)
        while (__hip_atomic_load(arr + (tid << 6), __ATOMIC_RELAXED,
                                 __HIP_MEMORY_SCOPE_AGENT) < ep)
          __builtin_amdgcn_s_sleep(1);
      __syncthreads();  // WAR on Hs (rec+xw reads of t-1 done) + poll half 1
    }
#pragma unroll
    for (int i = 0; i < 8; ++i)
      __builtin_amdgcn_global_load_lds(
          (const __attribute__((address_space(1))) void*)(src + i * 4096),
          (__attribute__((address_space(3))) void*)(dst + i * 4096), 16, 0, 0);
    if (t) {
      if (tid < 32)
        while (__hip_atomic_load(arr + ((32 + tid) << 6), __ATOMIC_RELAXED,
                                 __HIP_MEMORY_SCOPE_AGENT) < ep)
          __builtin_amdgcn_s_sleep(1);
      __syncthreads();
    }
#pragma unroll
    for (int i = 8; i < 16; ++i)
      __builtin_amdgcn_global_load_lds(
          (const __attribute__((address_space(1))) void*)(src + i * 4096),
          (__attribute__((address_space(3))) void*)(dst + i * 4096), 16, 0, 0);
    __syncthreads();  // staging complete

    f32x4 acc0 = cur0, acc1 = cur1;

    // prefetch next step's xW (this layer's values; row t+1 is overwritten
    // only at step t+2, so the in-place scheme is safe)
    if (t < 127) {
      const float* xb = xWp + (size_t)(t + 1) * 32 * 4096 + col4;
      cur0 = *(const f32x4*)(xb + (size_t)lrow * 4096);
      cur1 = *(const f32x4*)(xb + (size_t)(lrow + 16) * 4096);
    }

    // recurrent MFMA (swapped): acc = U-frag x h-frag
    const char* HsB = (const char*)Hs;
#pragma unroll
    for (int j = 0; j < 32; ++j) {
      int c0 = (2 * j + (lk >> 1)) * 1024 + lrow * 32 + (lk & 1) * 16;
      short8 b0 = *(const short8*)(HsB + c0);
      short8 b1 = *(const short8*)(HsB + c0 + 512);
      acc0 = __builtin_amdgcn_mfma_f32_16x16x32_bf16(ureg[j], b0, acc0, 0, 0, 0);
      acc1 = __builtin_amdgcn_mfma_f32_16x16x32_bf16(ureg[j], b1, acc1, 0, 0, 0);
    }

    // gates: all 4 in-lane (gate = reg index)
    int p0, p1;
    {
      float gi = 1.f / (1.f + __expf(-acc0[0]));
      float gf = 1.f / (1.f + __expf(-acc0[1]));
      float gg = fmaxf(acc0[2], 0.f);
      float go = 1.f / (1.f + __expf(-acc0[3]));
      float cn = gf * creg0 + gi * gg;
      creg0 = cn;
      p0 = (int)(unsigned short)bf16r(go * fmaxf(cn, 0.f));
    }
    {
      float gi = 1.f / (1.f + __expf(-acc1[0]));
      float gf = 1.f / (1.f + __expf(-acc1[1]));
      float gg = fmaxf(acc1[2], 0.f);
      float go = 1.f / (1.f + __expf(-acc1[3]));
      float cn = gf * creg1 + gi * gg;
      creg1 = cn;
      p1 = (int)(unsigned short)bf16r(go * fmaxf(cn, 0.f));
    }

    // pack 4 units -> u64; store to hx[t+1] (and hx[0] at t==127 if FUSE)
    {
      int a0 = __shfl(p0, lrow, 64);
      int a1 = __shfl(p0, lrow + 16, 64);
      int a2 = __shfl(p0, lrow + 32, 64);
      int a3 = __shfl(p0, lrow + 48, 64);
      int b0 = __shfl(p1, lrow, 64);
      int b1 = __shfl(p1, lrow + 16, 64);
      int b2 = __shfl(p1, lrow + 32, 64);
      int b3 = __shfl(p1, lrow + 48, 64);
      if (lk == 0) {
        short* hnx = hx + (size_t)(t + 1) * 32768 + bid * 512 + wave * 4;
        u64 pk0 = (u64)(unsigned)((a0 & 0xffff) | (a1 << 16)) |
                  ((u64)(unsigned)((a2 & 0xffff) | (a3 << 16)) << 32);
        u64 pk1 = (u64)(unsigned)((b0 & 0xffff) | (b1 << 16)) |
                  ((u64)(unsigned)((b2 & 0xffff) | (b3 << 16)) << 32);
        __hip_atomic_store((u64*)(hnx + lrow * 16), pk0, __ATOMIC_RELAXED,
                           __HIP_MEMORY_SCOPE_AGENT);
        __hip_atomic_store((u64*)(hnx + (lrow + 16) * 16), pk1, __ATOMIC_RELAXED,
                           __HIP_MEMORY_SCOPE_AGENT);
        if (FUSE && t == 127) {  // fold copy_h: h_final -> hx[0]
          short* hz = hx + bid * 512 + wave * 4;
          __hip_atomic_store((u64*)(hz + lrow * 16), pk0, __ATOMIC_RELAXED,
                             __HIP_MEMORY_SCOPE_AGENT);
          __hip_atomic_store((u64*)(hz + (lrow + 16) * 16), pk1,
                             __ATOMIC_RELAXED, __HIP_MEMORY_SCOPE_AGENT);
        }
      }
    }

    __syncthreads();  // drains h stores (vmcnt(0) before s_barrier)
    if (tid == 0)
      __hip_atomic_store(arr + (bid << 6), (unsigned)(ebase + t + 1),
                         __ATOMIC_RELAXED, __HIP_MEMORY_SCOPE_AGENT);

    // fused next-layer xW for row t-1 (Hs still holds h[t-1]); runs inside
    // the other blocks' detect window, off the exchange critical path.
    if constexpr (FUSE) {
      if (t) {
        f32x4 axw0 = bw, axw1 = bw;
#pragma unroll
        for (int j = 0; j < 32; ++j) {
          short8 wf8 = *(const short8*)(Wb + j * 32);
          int c0 = (2 * j + (lk >> 1)) * 1024 + lrow * 32 + (lk & 1) * 16;
          short8 b0 = *(const short8*)(HsB + c0);
          short8 b1 = *(const short8*)(HsB + c0 + 512);
          axw0 = __builtin_amdgcn_mfma_f32_16x16x32_bf16(wf8, b0, axw0, 0, 0, 0);
          axw1 = __builtin_amdgcn_mfma_f32_16x16x32_bf16(wf8, b1, axw1, 0, 0, 0);
        }
        float* xo = xWp + (size_t)(t - 1) * 32 * 4096 + col4;
        *(f32x4*)(xo + (size_t)lrow * 4096) = axw0;
        *(f32x4*)(xo + (size_t)(lrow + 16) * 4096) = axw1;
      }
    }
  }

  // epilogue (FUSE): one more exchange for h[127] -> xW row 127
  if constexpr (FUSE) {
    const unsigned ep = (unsigned)(ebase + 128);
    if (tid < 32) {
      while (__hip_atomic_load(arr + (tid << 6), __ATOMIC_RELAXED,
                               __HIP_MEMORY_SCOPE_AGENT) < ep)
        __builtin_amdgcn_s_sleep(1);
      while (__hip_atomic_load(arr + ((32 + tid) << 6), __ATOMIC_RELAXED,
                               __HIP_MEMORY_SCOPE_AGENT) < ep)
        __builtin_amdgcn_s_sleep(1);
    }
    __syncthreads();  // also WAR: xw reads of h[126] done
    const char* src = (const char*)(hx + (size_t)128 * 32768) + tid * 16;
    char* dst = (char*)Hs + tid * 16;
#pragma unroll
    for (int i = 0; i < 16; ++i)
      __builtin_amdgcn_global_load_lds(
          (const __attribute__((address_space(1))) void*)(src + i * 4096),
          (__attribute__((address_space(3))) void*)(dst + i * 4096), 16, 0, 0);
    __syncthreads();
    const char* HsB = (const char*)Hs;
    f32x4 axw0 = bw, axw1 = bw;
#pragma unroll
    for (int j = 0; j < 32; ++j) {
      short8 wf8 = *(const short8*)(Wb + j * 32);
      int c0 = (2 * j + (lk >> 1)) * 1024 + lrow * 32 + (lk & 1) * 16;
      short8 b0 = *(const short8*)(HsB + c0);
      short8 b1 = *(const short8*)(HsB + c0 + 512);
      axw0 = __builtin_amdgcn_mfma_f32_16x16x32_bf16(wf8, b0, axw0, 0, 0, 0);
      axw1 = __builtin_amdgcn_mfma_f32_16x16x32_bf16(wf8, b1, axw1, 0, 0, 0);
    }
    float* xo = xWp + (size_t)127 * 32 * 4096 + col4;
    *(f32x4*)(xo + (size_t)lrow * 4096) = axw0;
    *(f32x4*)(xo + (size_t)(lrow + 16) * 4096) = axw1;
  }

  cst[lrow * 1024 + u] = creg0;
  cst[(lrow + 16) * 1024 + u] = creg1;
}

// ---------- launch ----------
extern "C" void kernel_launch(void* const* d_in, const int* in_sizes, int n_in,
                              void* d_out, int out_size, void* d_ws, size_t ws_size,
                              hipStream_t stream) {
  const float* x = (const float*)d_in[0];
  const float* h0 = (const float*)d_in[1];
  const float* c0 = (const float*)d_in[2];
  const float* W[4] = {(const float*)d_in[3], (const float*)d_in[6],
                       (const float*)d_in[9], (const float*)d_in[12]};
  const float* U[4] = {(const float*)d_in[4], (const float*)d_in[7],
                       (const float*)d_in[10], (const float*)d_in[13]};
  const float* bv[4] = {(const float*)d_in[5], (const float*)d_in[8],
                        (const float*)d_in[11], (const float*)d_in[14]};
  const float* Wd1 = (const float*)d_in[15];
  const float* bd1 = (const float*)d_in[16];
  const float* Wd2 = (const float*)d_in[17];
  const float* bd2 = (const float*)d_in[18];
  float* out = (float*)d_out;

  float* ws = (float*)d_ws;
  float* xWp = ws;                               // 16,777,216 f (64MB)
  short* Utp = (short*)(ws + 16777216);          // 4,194,304 bf16
  short* Wtp = (short*)(ws + 18874368);          // 4,194,304 bf16
  short* Wf = (short*)(ws + 20971520);           // 4,194,304 bf16
  short* xb = (short*)(ws + 23068672);           // 2,097,152 bf16
  short* hx = (short*)(ws + 24117248);           // 129*32768 bf16
  float* cst = ws + 26230784;                    // 32,768 f
  float* bp = ws + 26263552;                     // 16,384 f
  unsigned* arr = (unsigned*)(ws + 26279936);    // 4,096 u32 epoch slots
  short* D1 = (short*)xWp;                       // alias: xWp dead by dense head

  zero_cnt<<<16, 256, 0, stream>>>(arr);
  init2<<<128, 256, 0, stream>>>(h0, c0, hx, cst);
  cast_x<<<8192, 256, 0, stream>>>(x, xb);
  bias_perm<<<64, 256, 0, stream>>>(bv[0], bv[1], bv[2], bv[3], bp);

  // layer 0's xW from the input GEMM
  transpose_cast<true><<<dim3(128, 16), 256, 0, stream>>>(W[0], Wtp, 512, 4096);
  gemm_bf16<1, false><<<dim3(32, 32), 256, 0, stream>>>(xb, Wtp, bp, xWp, 4096,
                                                        4096, 512);

  for (int l = 0; l < 4; ++l) {
    transpose_cast<true><<<dim3(128, 32), 256, 0, stream>>>(U[l], Utp, 1024, 4096);
    if (l < 3) {
      transpose_cast<true><<<dim3(128, 32), 256, 0, stream>>>(W[l + 1], Wf, 1024,
                                                              4096);
      lstm_persist<true><<<PBLK, 256, 0, stream>>>(
          xWp, Utp, Wf, bp + (l + 1) * 4096, hx, cst, arr, l * 256);
    } else {
      lstm_persist<false><<<PBLK, 256, 0, stream>>>(xWp, Utp, Wf, bp, hx, cst,
                                                    arr, l * 256);
    }
  }

  // dense head: A = layer-4 h sequence in hx layout
  transpose_cast<false><<<dim3(32, 32), 256, 0, stream>>>(Wd1, Wtp, 1024, 1024);
  gemm_bf16<2, true><<<dim3(8, 32), 256, 0, stream>>>(hx + 32768, Wtp, bd1, D1,
                                                      4096, 1024, 1024);
  transpose_cast<false><<<dim3(16, 32), 256, 0, stream>>>(Wd2, Wtp, 1024, 512);
  gemm_bf16<3, false><<<dim3(4, 32), 256, 0, stream>>>(D1, Wtp, bd2, out, 4096,
                                                       512, 1024);

  finalize2<<<128, 256, 0, stream>>>(hx + 128 * 32768, cst, out + 2097152);
}

// Round 10
// 2519.752 us; speedup vs baseline: 1.3109x; 1.3109x over previous
//
#include <hip/hip_runtime.h>
#include <cmath>

// B=32, T=128, E=512, H=1024, 4H=4096
typedef __attribute__((ext_vector_type(8))) short short8;
typedef __attribute__((ext_vector_type(4))) float f32x4;
typedef unsigned long long u64;

__device__ inline short bf16r(float x) {
  union { float f; unsigned u; } v; v.f = x;
  unsigned r = (v.u + 0x7fff + ((v.u >> 16) & 1)) >> 16;
  return (short)r;
}
__device__ inline float bf2f(short s) {
  union { unsigned u; float f; } v; v.u = ((unsigned)(unsigned short)s) << 16;
  return v.f;
}

// hx layout: [t][chunk c=u>>4][b(32)][u&15] bf16 ; 129 buffers of 32768 shorts.
// ---------- small prep kernels ----------
__global__ __launch_bounds__(256) void init2(const float* __restrict__ h0,
                                             const float* __restrict__ c0,
                                             short* __restrict__ hx0,
                                             float* __restrict__ c) {
  int idx = blockIdx.x * 256 + threadIdx.x;  // (b,u) row-major
  int b = idx >> 10, u = idx & 1023;
  hx0[(u >> 4) * 512 + b * 16 + (u & 15)] = bf16r(h0[idx]);
  c[idx] = c0[idx];
}

__global__ __launch_bounds__(256) void finalize2(const short* __restrict__ hx128,
                                                 const float* __restrict__ c,
                                                 float* __restrict__ out) {
  int idx = blockIdx.x * 256 + threadIdx.x;  // (b,u)
  int b = idx >> 10, u = idx & 1023;
  out[idx] = bf2f(hx128[(u >> 4) * 512 + b * 16 + (u & 15)]);
  out[32768 + idx] = c[idx];
}

__global__ __launch_bounds__(256) void zero_cnt(unsigned* __restrict__ c) {
  c[blockIdx.x * 256 + threadIdx.x] = 0u;  // 16 blocks -> 4096 u32
}

__global__ __launch_bounds__(256) void copy_h(const int* __restrict__ src,
                                              int* __restrict__ dst) {
  int i = blockIdx.x * 256 + threadIdx.x;  // 16384 ints = 64KB
  dst[i] = src[i];
}

// x (B,T,E) fp32 -> xb rows r=t*32+b, (4096,512) bf16
__global__ __launch_bounds__(256) void cast_x(const float* __restrict__ x,
                                              short* __restrict__ xb) {
  int idx = blockIdx.x * 256 + threadIdx.x;
  int e = idx & 511, t = (idx >> 9) & 127, b = idx >> 16;
  xb[(((t << 5) + b) << 9) + e] = bf16r(x[idx]);
}

// permuted biases: bp[l][n'] = b_l[(n'&3)*1024 + (n'>>2)]
__global__ __launch_bounds__(256) void bias_perm(const float* __restrict__ b1,
                                                 const float* __restrict__ b2,
                                                 const float* __restrict__ b3,
                                                 const float* __restrict__ b4,
                                                 float* __restrict__ bp) {
  int idx = blockIdx.x * 256 + threadIdx.x;  // 0..16383
  int l = idx >> 12, c = idx & 4095;
  const float* s = (l == 0) ? b1 : (l == 1) ? b2 : (l == 2) ? b3 : b4;
  bp[idx] = s[((c & 3) << 10) | (c >> 2)];
}

// in fp32 (R,C) -> out bf16 (C,R); GPERM: out-row n' = (c&1023)*4 + (c>>10)
template <bool GPERM>
__global__ __launch_bounds__(256) void transpose_cast(const float* __restrict__ in,
                                                      short* __restrict__ out,
                                                      int R, int C) {
  __shared__ float tile[32][33];
  int c0 = blockIdx.x * 32, r0 = blockIdx.y * 32;
  int x = threadIdx.x & 31, y = threadIdx.x >> 5;
#pragma unroll
  for (int i = 0; i < 4; ++i)
    tile[y + i * 8][x] = in[(size_t)(r0 + y + i * 8) * C + c0 + x];
  __syncthreads();
#pragma unroll
  for (int i = 0; i < 4; ++i) {
    int c = c0 + y + i * 8;
    int n = GPERM ? (((c & 1023) << 2) | (c >> 10)) : c;
    out[(size_t)n * R + r0 + x] = bf16r(tile[x][y + i * 8]);
  }
}

// ---------- bf16 MFMA GEMM ----------
// A: if AHX, A points at hx-layout sequence (row r=t*32+b, k=unit); else (M,K) rm.
// Bt (N,K) bf16 rm; C = A·Bt^T + bias
// MODE 1: fp32 out, row-major [r][col] ; MODE 2: bf16 rm + relu ; MODE 3: fp32 (B,T,E)
template <int MODE, bool AHX>
__global__ __launch_bounds__(256) void gemm_bf16(const short* __restrict__ A,
                                                 const short* __restrict__ Bt,
                                                 const float* __restrict__ bias,
                                                 void* __restrict__ Cout,
                                                 int M, int N, int K) {
  __shared__ short As[128 * 40];
  __shared__ short Bs[128 * 40];
  const int tid = threadIdx.x;
  const int lane = tid & 63, wave = tid >> 6;
  const int lrow = lane & 15, lk = lane >> 4;
  const int m0 = (wave >> 1) * 64, n0 = (wave & 1) * 64;
  const int r = tid & 127, half = tid >> 7;
  const int mbase = blockIdx.y * 128, nbase = blockIdx.x * 128;

  f32x4 acc[4][4] = {};

  const short* Ab = A + (size_t)(mbase + r) * K + half * 16;
  const short* Ahx =
      A + (size_t)((mbase + r) >> 5) * 32768 + half * 512 + ((mbase + r) & 31) * 16;
  const short* Bb = Bt + (size_t)(nbase + r) * K + half * 16;
  short* AsW = As + r * 40 + half * 16;
  short* BsW = Bs + r * 40 + half * 16;

  for (int k0 = 0; k0 < K; k0 += 32) {
    short8 av0, av1;
    if constexpr (AHX) {
      const short* ap = Ahx + (k0 >> 4) * 512;
      av0 = *(const short8*)ap;
      av1 = *(const short8*)(ap + 8);
    } else {
      av0 = *(const short8*)(Ab + k0);
      av1 = *(const short8*)(Ab + k0 + 8);
    }
    short8 bv0 = *(const short8*)(Bb + k0);
    short8 bv1 = *(const short8*)(Bb + k0 + 8);
    __syncthreads();
    *(short8*)(AsW) = av0;
    *(short8*)(AsW + 8) = av1;
    *(short8*)(BsW) = bv0;
    *(short8*)(BsW + 8) = bv1;
    __syncthreads();
    short8 af[4], bfr[4];
#pragma unroll
    for (int i = 0; i < 4; ++i)
      af[i] = *(const short8*)(As + (m0 + i * 16 + lrow) * 40 + lk * 8);
#pragma unroll
    for (int i = 0; i < 4; ++i)
      bfr[i] = *(const short8*)(Bs + (n0 + i * 16 + lrow) * 40 + lk * 8);
#pragma unroll
    for (int i = 0; i < 4; ++i)
#pragma unroll
      for (int j = 0; j < 4; ++j)
        acc[i][j] = __builtin_amdgcn_mfma_f32_16x16x32_bf16(af[i], bfr[j],
                                                            acc[i][j], 0, 0, 0);
  }

#pragma unroll
  for (int i = 0; i < 4; ++i) {
    const int grow0 = mbase + m0 + i * 16 + lk * 4;
#pragma unroll
    for (int j = 0; j < 4; ++j) {
      const int gcol = nbase + n0 + j * 16 + lrow;
      const float bv = bias[gcol];
      f32x4 v = acc[i][j];
      if constexpr (MODE == 1) {
        float* o = (float*)Cout;
#pragma unroll
        for (int jj = 0; jj < 4; ++jj)
          o[(size_t)(grow0 + jj) * N + gcol] = v[jj] + bv;
      } else if constexpr (MODE == 2) {
        short* o = (short*)Cout;
#pragma unroll
        for (int jj = 0; jj < 4; ++jj)
          o[(size_t)(grow0 + jj) * N + gcol] = bf16r(fmaxf(v[jj] + bv, 0.f));
      } else {
        float* o = (float*)Cout;
#pragma unroll
        for (int jj = 0; jj < 4; ++jj) {
          int rr = grow0 + jj;
          int orow = ((rr & 31) << 7) | (rr >> 5);
          o[(size_t)orow * N + gcol] = v[jj] + bv;
        }
      }
    }
  }
}

// ---------- persistent recurrent kernel (whole layer, 128 steps) ----------
// xWp [t*32+b][col] fp32 row-major; Utp (4096,1024) bf16 gate-interleaved;
// hx (129,32768) bf16 exchange [t][chunk][b][u16]; cst (32,1024) fp32.
// 64 blocks x 320 threads: waves 0-3 compute (16 cols each, swapped MFMA,
// gates in-lane); wave 4 = poller (polls 64 flags in 4 groups of 16, posts
// readiness to LDS so compute-wave vmcnt stays clean for counted waits).
// Step pipeline: spin(g)/issue(g) for 4x16KB groups + xW prefetch, then
// vmcnt(14)/bar/MFMA g0, vmcnt(10)/g1, vmcnt(4)/g2, vmcnt(0)/g3 (T3/T4).
#define PBLK 64
__global__ __launch_bounds__(320) void lstm_persist(
    const float* __restrict__ xWp, const short* __restrict__ Utp,
    short* __restrict__ hx, float* __restrict__ cst,
    unsigned* __restrict__ arr, int ebase) {
  __shared__ short Hs[32768];  // 64KB: h_t in chunk layout
  __shared__ unsigned ready[4];
  const int tid = threadIdx.x;
  const int lane = tid & 63, wave = tid >> 6;
  const int lrow = lane & 15, lk = lane >> 4;
  const int bid = blockIdx.x;
  const int ucol = bid * 64 + wave * 16 + lrow;    // A-operand row (U col)
  const int col4 = bid * 64 + wave * 16 + lk * 4;  // first z-col of this lane
  const int u = bid * 16 + wave * 4 + lk;          // unit owned by this lane

  short8 ureg[32];
  float creg0 = 0.f, creg1 = 0.f;
  f32x4 cur0 = {}, cur1 = {};
  if (wave < 4) {
    const short* Ub = Utp + (size_t)ucol * 1024 + lk * 8;
#pragma unroll
    for (int j = 0; j < 32; ++j) ureg[j] = *(const short8*)(Ub + j * 32);
    creg0 = cst[lrow * 1024 + u];
    creg1 = cst[(lrow + 16) * 1024 + u];
    cur0 = *(const f32x4*)(xWp + (size_t)lrow * 4096 + col4);
    cur1 = *(const f32x4*)(xWp + (size_t)(lrow + 16) * 4096 + col4);
  } else if (lane < 4) {
    ready[lane] = 0u;
  }
  __syncthreads();

  for (int t = 0; t < 128; ++t) {
    const unsigned ep = (unsigned)(ebase + t);
    f32x4 acc0, acc1;

    if (wave == 4) {
      // poller: detect the 4 flag groups in order, publish to LDS
      if (t) {
#pragma unroll
        for (int g = 0; g < 4; ++g) {
          if ((lane >> 4) == g) {
            const unsigned* fl = arr + ((g * 16 + (lane & 15)) << 6);
            while (__hip_atomic_load(fl, __ATOMIC_RELAXED,
                                     __HIP_MEMORY_SCOPE_AGENT) < ep)
              __builtin_amdgcn_s_sleep(1);
          }
          if (lane == 0)
            __hip_atomic_store(&ready[g], ep, __ATOMIC_RELAXED,
                               __HIP_MEMORY_SCOPE_WORKGROUP);
        }
      }
    } else {
      acc0 = cur0;
      acc1 = cur1;
      const char* src = (const char*)(hx + (size_t)t * 32768);
      char* dstb = (char*)Hs;
      const int off0 = wave * 4096 + lane * 16;
      // group 0
      if (t)
        while (__hip_atomic_load(&ready[0], __ATOMIC_RELAXED,
                                 __HIP_MEMORY_SCOPE_WORKGROUP) < ep) {}
#pragma unroll
      for (int q = 0; q < 4; ++q)
        __builtin_amdgcn_global_load_lds(
            (const __attribute__((address_space(1))) void*)(src + off0 + q * 1024),
            (__attribute__((address_space(3))) void*)(dstb + off0 + q * 1024),
            16, 0, 0);
      asm volatile("" ::: "memory");
      // group 1
      if (t)
        while (__hip_atomic_load(&ready[1], __ATOMIC_RELAXED,
                                 __HIP_MEMORY_SCOPE_WORKGROUP) < ep) {}
#pragma unroll
      for (int q = 0; q < 4; ++q)
        __builtin_amdgcn_global_load_lds(
            (const __attribute__((address_space(1))) void*)(src + 16384 + off0 +
                                                            q * 1024),
            (__attribute__((address_space(3))) void*)(dstb + 16384 + off0 +
                                                      q * 1024),
            16, 0, 0);
      asm volatile("" ::: "memory");
      // xW prefetch for next step (2 dwordx4 loads -> vmcnt slots 9,10)
      {
        const int tn = t < 127 ? t + 1 : t;
        const float* xb = xWp + (size_t)tn * 32 * 4096 + col4;
        cur0 = *(const f32x4*)(xb + (size_t)lrow * 4096);
        cur1 = *(const f32x4*)(xb + (size_t)(lrow + 16) * 4096);
      }
      asm volatile("" ::: "memory");
      // group 2
      if (t)
        while (__hip_atomic_load(&ready[2], __ATOMIC_RELAXED,
                                 __HIP_MEMORY_SCOPE_WORKGROUP) < ep) {}
#pragma unroll
      for (int q = 0; q < 4; ++q)
        __builtin_amdgcn_global_load_lds(
            (const __attribute__((address_space(1))) void*)(src + 32768 + off0 +
                                                            q * 1024),
            (__attribute__((address_space(3))) void*)(dstb + 32768 + off0 +
                                                      q * 1024),
            16, 0, 0);
      asm volatile("" ::: "memory");
      // group 3
      if (t)
        while (__hip_atomic_load(&ready[3], __ATOMIC_RELAXED,
                                 __HIP_MEMORY_SCOPE_WORKGROUP) < ep) {}
#pragma unroll
      for (int q = 0; q < 4; ++q)
        __builtin_amdgcn_global_load_lds(
            (const __attribute__((address_space(1))) void*)(src + 49152 + off0 +
                                                            q * 1024),
            (__attribute__((address_space(3))) void*)(dstb + 49152 + off0 +
                                                      q * 1024),
            16, 0, 0);
      asm volatile("s_waitcnt vmcnt(14)" ::: "memory");  // group 0 staged
    }

    __builtin_amdgcn_s_barrier();
    __builtin_amdgcn_sched_barrier(0);
    const char* HsB = (const char*)Hs;
    if (wave < 4) {
#pragma unroll
      for (int j = 0; j < 8; ++j) {
        int c0 = (2 * j + (lk >> 1)) * 1024 + lrow * 32 + (lk & 1) * 16;
        short8 b0 = *(const short8*)(HsB + c0);
        short8 b1 = *(const short8*)(HsB + c0 + 512);
        acc0 = __builtin_amdgcn_mfma_f32_16x16x32_bf16(ureg[j], b0, acc0, 0, 0, 0);
        acc1 = __builtin_amdgcn_mfma_f32_16x16x32_bf16(ureg[j], b1, acc1, 0, 0, 0);
      }
      asm volatile("s_waitcnt vmcnt(10)" ::: "memory");  // group 1 staged
    }
    __builtin_amdgcn_s_barrier();
    __builtin_amdgcn_sched_barrier(0);
    if (wave < 4) {
#pragma unroll
      for (int j = 8; j < 16; ++j) {
        int c0 = (2 * j + (lk >> 1)) * 1024 + lrow * 32 + (lk & 1) * 16;
        short8 b0 = *(const short8*)(HsB + c0);
        short8 b1 = *(const short8*)(HsB + c0 + 512);
        acc0 = __builtin_amdgcn_mfma_f32_16x16x32_bf16(ureg[j], b0, acc0, 0, 0, 0);
        acc1 = __builtin_amdgcn_mfma_f32_16x16x32_bf16(ureg[j], b1, acc1, 0, 0, 0);
      }
      asm volatile("s_waitcnt vmcnt(4)" ::: "memory");  // group 2 (+prefetch)
    }
    __builtin_amdgcn_s_barrier();
    __builtin_amdgcn_sched_barrier(0);
    if (wave < 4) {
#pragma unroll
      for (int j = 16; j < 24; ++j) {
        int c0 = (2 * j + (lk >> 1)) * 1024 + lrow * 32 + (lk & 1) * 16;
        short8 b0 = *(const short8*)(HsB + c0);
        short8 b1 = *(const short8*)(HsB + c0 + 512);
        acc0 = __builtin_amdgcn_mfma_f32_16x16x32_bf16(ureg[j], b0, acc0, 0, 0, 0);
        acc1 = __builtin_amdgcn_mfma_f32_16x16x32_bf16(ureg[j], b1, acc1, 0, 0, 0);
      }
      asm volatile("s_waitcnt vmcnt(0)" ::: "memory");  // group 3 staged
    }
    __builtin_amdgcn_s_barrier();
    __builtin_amdgcn_sched_barrier(0);
    if (wave < 4) {
#pragma unroll
      for (int j = 24; j < 32; ++j) {
        int c0 = (2 * j + (lk >> 1)) * 1024 + lrow * 32 + (lk & 1) * 16;
        short8 b0 = *(const short8*)(HsB + c0);
        short8 b1 = *(const short8*)(HsB + c0 + 512);
        acc0 = __builtin_amdgcn_mfma_f32_16x16x32_bf16(ureg[j], b0, acc0, 0, 0, 0);
        acc1 = __builtin_amdgcn_mfma_f32_16x16x32_bf16(ureg[j], b1, acc1, 0, 0, 0);
      }

      // gates: all 4 in-lane (gate = reg index)
      int p0, p1;
      {
        float gi = 1.f / (1.f + __expf(-acc0[0]));
        float gf = 1.f / (1.f + __expf(-acc0[1]));
        float gg = fmaxf(acc0[2], 0.f);
        float go = 1.f / (1.f + __expf(-acc0[3]));
        float cn = gf * creg0 + gi * gg;
        creg0 = cn;
        p0 = (int)(unsigned short)bf16r(go * fmaxf(cn, 0.f));
      }
      {
        float gi = 1.f / (1.f + __expf(-acc1[0]));
        float gf = 1.f / (1.f + __expf(-acc1[1]));
        float gg = fmaxf(acc1[2], 0.f);
        float go = 1.f / (1.f + __expf(-acc1[3]));
        float cn = gf * creg1 + gi * gg;
        creg1 = cn;
        p1 = (int)(unsigned short)bf16r(go * fmaxf(cn, 0.f));
      }

      // pack: u64 = 4 units (lk 0..3) of this wave for one b; 8 shfl total
      int a0 = __shfl(p0, lrow, 64);
      int a1 = __shfl(p0, lrow + 16, 64);
      int a2 = __shfl(p0, lrow + 32, 64);
      int a3 = __shfl(p0, lrow + 48, 64);
      int b0 = __shfl(p1, lrow, 64);
      int b1 = __shfl(p1, lrow + 16, 64);
      int b2 = __shfl(p1, lrow + 32, 64);
      int b3 = __shfl(p1, lrow + 48, 64);
      if (lk == 0) {
        short* hnx = hx + (size_t)(t + 1) * 32768 + bid * 512 + wave * 4;
        u64 pk0 = (u64)(unsigned)((a0 & 0xffff) | (a1 << 16)) |
                  ((u64)(unsigned)((a2 & 0xffff) | (a3 << 16)) << 32);
        u64 pk1 = (u64)(unsigned)((b0 & 0xffff) | (b1 << 16)) |
                  ((u64)(unsigned)((b2 & 0xffff) | (b3 << 16)) << 32);
        __hip_atomic_store((u64*)(hnx + lrow * 16), pk0, __ATOMIC_RELAXED,
                           __HIP_MEMORY_SCOPE_AGENT);
        __hip_atomic_store((u64*)(hnx + (lrow + 16) * 16), pk1, __ATOMIC_RELAXED,
                           __HIP_MEMORY_SCOPE_AGENT);
      }
    }

    if (t != 127) {
      __syncthreads();  // drains h stores (vmcnt(0)+barrier), WAR on Hs
      if (tid == 0)
        __hip_atomic_store(arr + (bid << 6), (unsigned)(ebase + t + 1),
                           __ATOMIC_RELAXED, __HIP_MEMORY_SCOPE_AGENT);
    }
  }

  if (wave < 4) {
    cst[lrow * 1024 + u] = creg0;
    cst[(lrow + 16) * 1024 + u] = creg1;
  }
}

// ---------- launch ----------
extern "C" void kernel_launch(void* const* d_in, const int* in_sizes, int n_in,
                              void* d_out, int out_size, void* d_ws, size_t ws_size,
                              hipStream_t stream) {
  const float* x = (const float*)d_in[0];
  const float* h0 = (const float*)d_in[1];
  const float* c0 = (const float*)d_in[2];
  const float* W[4] = {(const float*)d_in[3], (const float*)d_in[6],
                       (const float*)d_in[9], (const float*)d_in[12]};
  const float* U[4] = {(const float*)d_in[4], (const float*)d_in[7],
                       (const float*)d_in[10], (const float*)d_in[13]};
  const float* bv[4] = {(const float*)d_in[5], (const float*)d_in[8],
                        (const float*)d_in[11], (const float*)d_in[14]};
  const float* Wd1 = (const float*)d_in[15];
  const float* bd1 = (const float*)d_in[16];
  const float* Wd2 = (const float*)d_in[17];
  const float* bd2 = (const float*)d_in[18];
  float* out = (float*)d_out;

  float* ws = (float*)d_ws;
  float* xWp = ws;                               // 16,777,216 f (64MB)
  short* Utp = (short*)(ws + 16777216);          // 4,194,304 bf16
  short* Wtp = (short*)(ws + 18874368);          // 4,194,304 bf16
  short* xb = (short*)(ws + 20971520);           // 2,097,152 bf16
  short* hx = (short*)(ws + 22020096);           // 129*32768 bf16
  float* cst = ws + 24133632;                    // 32,768 f
  float* bp = ws + 24166400;                     // 16,384 f
  unsigned* arr = (unsigned*)(ws + 24182784);    // 4,096 u32 epoch slots
  short* D1 = (short*)xWp;                       // alias: xWp dead by dense head

  zero_cnt<<<16, 256, 0, stream>>>(arr);
  init2<<<128, 256, 0, stream>>>(h0, c0, hx, cst);
  cast_x<<<8192, 256, 0, stream>>>(x, xb);
  bias_perm<<<64, 256, 0, stream>>>(bv[0], bv[1], bv[2], bv[3], bp);

  for (int l = 0; l < 4; ++l) {
    const int K = (l == 0) ? 512 : 1024;
    transpose_cast<true><<<dim3(128, 32), 256, 0, stream>>>(U[l], Utp, 1024, 4096);
    transpose_cast<true><<<dim3(128, K / 32), 256, 0, stream>>>(W[l], Wtp, K, 4096);
    if (l == 0) {
      gemm_bf16<1, false><<<dim3(32, 32), 256, 0, stream>>>(
          xb, Wtp, bp, xWp, 4096, 4096, 512);
    } else {
      gemm_bf16<1, true><<<dim3(32, 32), 256, 0, stream>>>(
          hx + 32768, Wtp, bp + l * 4096, xWp, 4096, 4096, 1024);
      copy_h<<<64, 256, 0, stream>>>((const int*)(hx + 128 * 32768), (int*)hx);
    }
    lstm_persist<<<PBLK, 320, 0, stream>>>(xWp, Utp, hx, cst, arr, l * 128);
  }

  // dense head: A = layer-4 h sequence in hx layout
  transpose_cast<false><<<dim3(32, 32), 256, 0, stream>>>(Wd1, Wtp, 1024, 1024);
  gemm_bf16<2, true><<<dim3(8, 32), 256, 0, stream>>>(hx + 32768, Wtp, bd1, D1,
                                                      4096, 1024, 1024);
  transpose_cast<false><<<dim3(16, 32), 256, 0, stream>>>(Wd2, Wtp, 1024, 512);
  gemm_bf16<3, false><<<dim3(4, 32), 256, 0, stream>>>(D1, Wtp, bd2, out, 4096,
                                                       512, 1024);

  finalize2<<<128, 256, 0, stream>>>(hx + 128 * 32768, cst, out + 2097152);
}